// Round 8
// baseline (346.428 us; speedup 1.0000x reference)
//
#include <hip/hip_runtime.h>
#include <hip/hip_cooperative_groups.h>

namespace cg = cooperative_groups;

#define NSEG 16
#define CIN 64
#define COUT 128
#define BN_EPS 1e-5f
#define GRID_BLKS 1024

typedef float vf4 __attribute__((ext_vector_type(4)));

// ---- index dtype hedge: int64 per reference, int32 if JAX x64 is off.
// Viewing as int32: element N-1 is 15 (last sorted value) if int32, 0 if int64.
__device__ __forceinline__ bool idx_is64(const void* p, int N) {
    return ((const int*)p)[N - 1] == 0;
}
__device__ __forceinline__ int load_idx(const void* p, long long i, bool is64) {
    return is64 ? (int)((const long long*)p)[i] : ((const int*)p)[i];
}

// ws layout (4-byte units): [0,1024) seg_sum[16][64]; [1024,1040) gcnt[16].
// memset zeroes [0,1040).

// Fused cooperative kernel: segsum -> grid.sync -> per-block MLP/BN/ReLU
// (redundant, LDS-resident) -> gather with NT stores. Lean registers:
// launch_bounds(256,4) guarantees 4 blocks/CU so all 1024 blocks co-reside.
__global__ __launch_bounds__(256, 4) void k_fused(
    const float* __restrict__ feat, const void* __restrict__ idxp,
    const float* __restrict__ W, const float* __restrict__ gamma,
    const float* __restrict__ beta,
    float* __restrict__ seg_sum, int* __restrict__ gcnt,
    float* __restrict__ out, int N, int rpb_sum, int rpb_gat)
{
    __shared__ float acc_lds[NSEG * CIN];   // 4 KB: partials, then pooled
    __shared__ int   cnt_lds[NSEG];
    __shared__ float h_lds[NSEG * COUT];    // 8 KB: final h (never global)
    __shared__ float scale_s[COUT], bias_s[COUT];

    const int tid = threadIdx.x;
    const bool is64 = idx_is64(idxp, N);

    // ---------------- phase 1: segment-sum + counts ----------------
    for (int i = tid; i < NSEG * CIN; i += 256) acc_lds[i] = 0.0f;
    if (tid < NSEG) cnt_lds[tid] = 0;
    __syncthreads();
    {
        const int row0 = blockIdx.x * rpb_sum;
        const int row_end = min(row0 + rpb_sum, N);
        const int q  = tid & 15;   // vf4 chunk within row (row = 16 vf4)
        const int rp = tid >> 4;   // row phase 0..15
        const vf4* feat4 = (const vf4*)feat;
        if (row0 < row_end) {
            const int s0 = load_idx(idxp, row0, is64);
            const int s1 = load_idx(idxp, row_end - 1, is64);
            if (s0 == s1) {        // fast path: pure float4 stream
                vf4 acc = {0.f, 0.f, 0.f, 0.f};
                #pragma unroll 4
                for (int r = row0 + rp; r < row_end; r += 16)
                    acc += feat4[(size_t)r * 16 + q];
                atomicAdd(&acc_lds[s0 * CIN + q * 4 + 0], acc.x);
                atomicAdd(&acc_lds[s0 * CIN + q * 4 + 1], acc.y);
                atomicAdd(&acc_lds[s0 * CIN + q * 4 + 2], acc.z);
                atomicAdd(&acc_lds[s0 * CIN + q * 4 + 3], acc.w);
                if (tid == 0) cnt_lds[s0] = row_end - row0;
            } else {               // boundary blocks (<=15)
                vf4 acc = {0.f, 0.f, 0.f, 0.f};
                int cur = -1, run = 0;
                for (int r = row0 + rp; r < row_end; r += 16) {
                    const int s = load_idx(idxp, r, is64);
                    if (s != cur) {
                        if (cur >= 0) {
                            atomicAdd(&acc_lds[cur * CIN + q * 4 + 0], acc.x);
                            atomicAdd(&acc_lds[cur * CIN + q * 4 + 1], acc.y);
                            atomicAdd(&acc_lds[cur * CIN + q * 4 + 2], acc.z);
                            atomicAdd(&acc_lds[cur * CIN + q * 4 + 3], acc.w);
                            if (q == 0) atomicAdd(&cnt_lds[cur], run);
                        }
                        acc = (vf4){0.f, 0.f, 0.f, 0.f};
                        run = 0; cur = s;
                    }
                    acc += feat4[(size_t)r * 16 + q];
                    ++run;
                }
                if (cur >= 0) {
                    atomicAdd(&acc_lds[cur * CIN + q * 4 + 0], acc.x);
                    atomicAdd(&acc_lds[cur * CIN + q * 4 + 1], acc.y);
                    atomicAdd(&acc_lds[cur * CIN + q * 4 + 2], acc.z);
                    atomicAdd(&acc_lds[cur * CIN + q * 4 + 3], acc.w);
                    if (q == 0) atomicAdd(&cnt_lds[cur], run);
                }
            }
        }
        __syncthreads();
        for (int i = tid; i < NSEG * CIN; i += 256) {
            const float v = acc_lds[i];
            if (v != 0.0f) atomicAdd(&seg_sum[i], v);
        }
        if (tid < NSEG && cnt_lds[tid] != 0) atomicAdd(&gcnt[tid], cnt_lds[tid]);
    }

    cg::this_grid().sync();

    // ------- phase 2: per-block redundant pooled -> MLP -> BN -> ReLU -------
    // Agent-scope atomic loads: cross-XCD visibility of phase-1 atomics.
    if (tid < NSEG) {
        const int c = __hip_atomic_load(&gcnt[tid], __ATOMIC_RELAXED,
                                        __HIP_MEMORY_SCOPE_AGENT);
        cnt_lds[tid] = max(c, 1);
    }
    __syncthreads();
    for (int i = tid; i < NSEG * CIN; i += 256) {
        const float v = __hip_atomic_load(&seg_sum[i], __ATOMIC_RELAXED,
                                          __HIP_MEMORY_SCOPE_AGENT);
        acc_lds[i] = v / (float)cnt_lds[i >> 6];     // pooled, in place
    }
    __syncthreads();

    {
        const vf4* W4 = (const vf4*)W;
        const vf4* P4 = (const vf4*)acc_lds;
        for (int k = 0; k < 8; ++k) {                // sequential: low VGPR
            const int o = tid + k * 256;             // [0,2048)
            const int b = o >> 7, co = o & 127;
            vf4 s4 = {0.f, 0.f, 0.f, 0.f};
            #pragma unroll 4
            for (int c4 = 0; c4 < 16; ++c4)
                s4 += W4[co * 16 + c4] * P4[b * 16 + c4];
            h_lds[o] = s4.x + s4.y + s4.z + s4.w;
        }
    }
    __syncthreads();
    if (tid < COUT) {
        float m = 0.f;
        #pragma unroll
        for (int b = 0; b < NSEG; ++b) m += h_lds[b * COUT + tid];
        m *= (1.0f / NSEG);
        float v = 0.f;
        #pragma unroll
        for (int b = 0; b < NSEG; ++b) {
            const float d = h_lds[b * COUT + tid] - m;
            v += d * d;
        }
        v *= (1.0f / NSEG);
        const float sc = gamma[tid] * rsqrtf(v + BN_EPS);
        scale_s[tid] = sc;
        bias_s[tid] = beta[tid] - m * sc;
    }
    __syncthreads();
    for (int k = 0; k < 8; ++k) {
        const int o = tid + k * 256;
        const int co = o & 127;
        h_lds[o] = fmaxf(h_lds[o] * scale_s[co] + bias_s[co], 0.0f);
    }
    __syncthreads();

    // ---------------- phase 3: gather (NT stores from LDS) ----------------
    {
        const int row0 = blockIdx.x * rpb_gat;
        const int row_end = min(row0 + rpb_gat, N);
        if (row0 >= row_end) return;
        const int q = tid & 31;      // vf4 within row (row = 32 vf4)
        const int rofs = tid >> 5;   // 0..7
        vf4* out4 = (vf4*)out;
        const vf4* h4 = (const vf4*)h_lds;
        const int s0 = load_idx(idxp, row0, is64);
        const int s1 = load_idx(idxp, row_end - 1, is64);
        if (s0 == s1) {
            const vf4 pat = h4[s0 * 32 + q];
            #pragma unroll 4
            for (int r = row0 + rofs; r < row_end; r += 8)
                __builtin_nontemporal_store(pat, &out4[(size_t)r * 32 + q]);
        } else {
            int cur = -1; vf4 pat = {0.f, 0.f, 0.f, 0.f};
            for (int r = row0 + rofs; r < row_end; r += 8) {
                const int s = load_idx(idxp, r, is64);
                if (s != cur) { pat = h4[s * 32 + q]; cur = s; }
                __builtin_nontemporal_store(pat, &out4[(size_t)r * 32 + q]);
            }
        }
    }
}

extern "C" void kernel_launch(void* const* d_in, const int* in_sizes, int n_in,
                              void* d_out, int out_size, void* d_ws, size_t ws_size,
                              hipStream_t stream) {
    const float* feat  = (const float*)d_in[0];
    const float* W     = (const float*)d_in[1];
    const float* gamma = (const float*)d_in[2];
    const float* beta  = (const float*)d_in[3];
    const void*  idx   = d_in[4];
    int N = in_sizes[4];

    float* seg_sum = (float*)d_ws;
    int*   gcnt    = (int*)d_ws + 1024;
    float* out     = (float*)d_out;

    hipMemsetAsync(d_ws, 0, 1040 * sizeof(int), stream);

    int rpb_sum = ((((N + GRID_BLKS - 1) / GRID_BLKS)) + 15) & ~15;
    int rpb_gat = ((((N + GRID_BLKS - 1) / GRID_BLKS)) + 7) & ~7;

    void* args[] = {
        (void*)&feat, (void*)&idx, (void*)&W, (void*)&gamma, (void*)&beta,
        (void*)&seg_sum, (void*)&gcnt, (void*)&out,
        (void*)&N, (void*)&rpb_sum, (void*)&rpb_gat,
    };
    hipLaunchCooperativeKernel((void*)k_fused, dim3(GRID_BLKS), dim3(256),
                               args, 0, stream);
}

// Round 9
// 187.941 us; speedup vs baseline: 1.8433x; 1.8433x over previous
//
#include <hip/hip_runtime.h>

#define NSEG 16
#define CIN 64
#define COUT 128
#define BN_EPS 1e-5f

typedef float vf4 __attribute__((ext_vector_type(4)));

// ---- index dtype hedge: int64 per reference, int32 if JAX x64 is off.
// Viewing as int32: element N-1 is 15 (last sorted value) if int32, 0 if int64.
__device__ __forceinline__ bool idx_is64(const void* p, int N) {
    return ((const int*)p)[N - 1] == 0;
}
__device__ __forceinline__ int load_idx(const void* p, long long i, bool is64) {
    return is64 ? (int)((const long long*)p)[i] : ((const int*)p)[i];
}

// ws layout (4-byte units):
//   [0,1024)    float seg_sum[16][64]
//   [1024,1040) int   gcnt[16]
//   [1056,3104) float h_final[16][128]

// K0: zero accumulators. Own kernel (hipMemsetAsync produces pathological
// tiny fill dispatches on this stack -- R5/R6/R7 evidence).
__global__ __launch_bounds__(256) void k_zero(int* __restrict__ wsi) {
    const int i = threadIdx.x;
    ((float*)wsi)[i] = 0.0f;          // seg_sum[0..255]
    ((float*)wsi)[i + 256] = 0.0f;
    ((float*)wsi)[i + 512] = 0.0f;
    ((float*)wsi)[i + 768] = 0.0f;
    if (i < NSEG) wsi[1024 + i] = 0;  // gcnt
}

// K1: segment-sum + counts. Geometry = R1 best (~992 rows/block, 1009 blocks).
// Fast path (single-segment block, ~99%): pure float4 stream, 2 idx probes.
__global__ __launch_bounds__(256) void k_segsum(
    const float* __restrict__ feat, const void* __restrict__ idxp,
    float* __restrict__ seg_sum, int* __restrict__ gcnt,
    int N, int rows_per_blk)
{
    __shared__ float acc_lds[NSEG * CIN];
    __shared__ int   cnt_lds[NSEG];
    const int tid = threadIdx.x;
    for (int i = tid; i < NSEG * CIN; i += 256) acc_lds[i] = 0.0f;
    if (tid < NSEG) cnt_lds[tid] = 0;
    __syncthreads();

    const bool is64 = idx_is64(idxp, N);
    const int row0 = blockIdx.x * rows_per_blk;
    const int row_end = min(row0 + rows_per_blk, N);
    const int q  = tid & 15;    // vf4 chunk within row (row = 16 vf4)
    const int rp = tid >> 4;    // row phase 0..15
    const vf4* feat4 = (const vf4*)feat;

    if (row0 < row_end) {
        const int s0 = load_idx(idxp, row0, is64);
        const int s1 = load_idx(idxp, row_end - 1, is64);
        if (s0 == s1) {
            vf4 acc = {0.f, 0.f, 0.f, 0.f};
            #pragma unroll 4
            for (int r = row0 + rp; r < row_end; r += 16)
                acc += feat4[(size_t)r * 16 + q];
            atomicAdd(&acc_lds[s0 * CIN + q * 4 + 0], acc.x);
            atomicAdd(&acc_lds[s0 * CIN + q * 4 + 1], acc.y);
            atomicAdd(&acc_lds[s0 * CIN + q * 4 + 2], acc.z);
            atomicAdd(&acc_lds[s0 * CIN + q * 4 + 3], acc.w);
            if (tid == 0) cnt_lds[s0] = row_end - row0;
        } else {
            // boundary blocks (<=15): per-row idx, run-accumulate
            vf4 acc = {0.f, 0.f, 0.f, 0.f};
            int cur = -1, run = 0;
            for (int r = row0 + rp; r < row_end; r += 16) {
                const int s = load_idx(idxp, r, is64);
                if (s != cur) {
                    if (cur >= 0) {
                        atomicAdd(&acc_lds[cur * CIN + q * 4 + 0], acc.x);
                        atomicAdd(&acc_lds[cur * CIN + q * 4 + 1], acc.y);
                        atomicAdd(&acc_lds[cur * CIN + q * 4 + 2], acc.z);
                        atomicAdd(&acc_lds[cur * CIN + q * 4 + 3], acc.w);
                        if (q == 0) atomicAdd(&cnt_lds[cur], run);
                    }
                    acc = (vf4){0.f, 0.f, 0.f, 0.f};
                    run = 0; cur = s;
                }
                acc += feat4[(size_t)r * 16 + q];
                ++run;
            }
            if (cur >= 0) {
                atomicAdd(&acc_lds[cur * CIN + q * 4 + 0], acc.x);
                atomicAdd(&acc_lds[cur * CIN + q * 4 + 1], acc.y);
                atomicAdd(&acc_lds[cur * CIN + q * 4 + 2], acc.z);
                atomicAdd(&acc_lds[cur * CIN + q * 4 + 3], acc.w);
                if (q == 0) atomicAdd(&cnt_lds[cur], run);
            }
        }
    }
    __syncthreads();
    for (int i = tid; i < NSEG * CIN; i += 256) {
        const float v = acc_lds[i];
        if (v != 0.0f) atomicAdd(&seg_sum[i], v);
    }
    if (tid < NSEG && cnt_lds[tid] != 0) atomicAdd(&gcnt[tid], cnt_lds[tid]);
}

// K2: single block: pooled mean -> 16x64 @ 64x128 -> BN(biased) -> ReLU.
// Counts come from gcnt (no serial binary-search latency chain).
__global__ __launch_bounds__(256) void k_mlp(
    const float* __restrict__ seg_sum, const int* __restrict__ gcnt,
    const float* __restrict__ W, const float* __restrict__ gamma,
    const float* __restrict__ beta, float* __restrict__ h_final)
{
    __shared__ float pooled[NSEG * CIN];
    __shared__ float h_lds[NSEG * COUT];
    __shared__ float cnt[NSEG];
    __shared__ float scale_s[COUT], bias_s[COUT];
    const int tid = threadIdx.x;

    if (tid < NSEG) cnt[tid] = (float)max(gcnt[tid], 1);
    __syncthreads();
    for (int i = tid; i < NSEG * CIN; i += 256) pooled[i] = seg_sum[i] / cnt[i >> 6];
    __syncthreads();

    const vf4* W4 = (const vf4*)W;
    const vf4* P4 = (const vf4*)pooled;
    #pragma unroll
    for (int k = 0; k < 8; ++k) {
        const int o = tid + k * 256;           // [0,2048)
        const int b = o >> 7, co = o & 127;
        vf4 s4 = {0.f, 0.f, 0.f, 0.f};
        #pragma unroll
        for (int c4 = 0; c4 < 16; ++c4)
            s4 += W4[co * 16 + c4] * P4[b * 16 + c4];
        h_lds[o] = s4.x + s4.y + s4.z + s4.w;
    }
    __syncthreads();
    if (tid < COUT) {
        float m = 0.f;
        #pragma unroll
        for (int b = 0; b < NSEG; ++b) m += h_lds[b * COUT + tid];
        m *= (1.0f / NSEG);
        float v = 0.f;
        #pragma unroll
        for (int b = 0; b < NSEG; ++b) {
            const float d = h_lds[b * COUT + tid] - m;
            v += d * d;
        }
        v *= (1.0f / NSEG);
        const float sc = gamma[tid] * rsqrtf(v + BN_EPS);
        scale_s[tid] = sc;
        bias_s[tid] = beta[tid] - m * sc;
    }
    __syncthreads();
    #pragma unroll
    for (int k = 0; k < 8; ++k) {
        const int o = tid + k * 256;
        const int co = o & 127;
        h_final[o] = fmaxf(h_lds[o] * scale_s[co] + bias_s[co], 0.0f);
    }
}

// K3: gather. Probe fast path; NT stores are MANDATORY (R7: plain stores
// thrash L2 on the 512 MB stream, +55 us).
__global__ __launch_bounds__(256) void k_gather(
    const float* __restrict__ h_final, const void* __restrict__ idxp,
    float* __restrict__ out, int N, int rows_per_blk)
{
    __shared__ vf4 h4[NSEG * 32];
    const int tid = threadIdx.x;
    for (int i = tid; i < NSEG * 32; i += 256) h4[i] = ((const vf4*)h_final)[i];
    __syncthreads();

    const int row0 = blockIdx.x * rows_per_blk;
    const int row_end = min(row0 + rows_per_blk, N);
    if (row0 >= row_end) return;
    const bool is64 = idx_is64(idxp, N);
    const int q = tid & 31;       // vf4 within row (row = 32 vf4)
    const int rofs = tid >> 5;    // 0..7
    vf4* out4 = (vf4*)out;

    const int s0 = load_idx(idxp, row0, is64);
    const int s1 = load_idx(idxp, row_end - 1, is64);
    if (s0 == s1) {
        const vf4 pat = h4[s0 * 32 + q];
        #pragma unroll 4
        for (int r = row0 + rofs; r < row_end; r += 8)
            __builtin_nontemporal_store(pat, &out4[(size_t)r * 32 + q]);
    } else {
        int cur = -1; vf4 pat = {0.f, 0.f, 0.f, 0.f};
        for (int r = row0 + rofs; r < row_end; r += 8) {
            const int s = load_idx(idxp, r, is64);
            if (s != cur) { pat = h4[s * 32 + q]; cur = s; }
            __builtin_nontemporal_store(pat, &out4[(size_t)r * 32 + q]);
        }
    }
}

extern "C" void kernel_launch(void* const* d_in, const int* in_sizes, int n_in,
                              void* d_out, int out_size, void* d_ws, size_t ws_size,
                              hipStream_t stream) {
    const float* feat  = (const float*)d_in[0];
    const float* W     = (const float*)d_in[1];
    const float* gamma = (const float*)d_in[2];
    const float* beta  = (const float*)d_in[3];
    const void*  idx   = d_in[4];
    const int N = in_sizes[4];

    float* seg_sum = (float*)d_ws;
    int*   gcnt    = (int*)d_ws + 1024;
    float* h_final = (float*)d_ws + 1056;

    hipLaunchKernelGGL(k_zero, dim3(1), dim3(256), 0, stream, (int*)d_ws);

    // R1-best geometry: ~992 rows/block -> 1009 blocks.
    const int NB1 = 1024;
    const int rpb1 = (((N + NB1 - 1) / NB1) + 15) & ~15;
    const int nb1 = (N + rpb1 - 1) / rpb1;
    hipLaunchKernelGGL(k_segsum, dim3(nb1), dim3(256), 0, stream,
                       feat, idx, seg_sum, gcnt, N, rpb1);

    hipLaunchKernelGGL(k_mlp, dim3(1), dim3(256), 0, stream,
                       seg_sum, gcnt, W, gamma, beta, h_final);

    const int NB2 = 2048;
    const int rpb2 = (((N + NB2 - 1) / NB2) + 7) & ~7;
    const int nb2 = (N + rpb2 - 1) / rpb2;
    hipLaunchKernelGGL(k_gather, dim3(nb2), dim3(256), 0, stream,
                       h_final, idx, (float*)d_out, N, rpb2);
}

// Round 10
// 154.297 us; speedup vs baseline: 2.2452x; 1.2181x over previous
//
#include <hip/hip_runtime.h>

#define NSEG 16
#define CIN 64
#define COUT 128
#define BN_EPS 1e-5f

typedef float vf4 __attribute__((ext_vector_type(4)));

// ---- index dtype hedge: reference says int64 but JAX default-x64-off makes int32.
// Viewing buffer as int32: element N-1 is 15 (last sorted value) if int32,
// but 0 (high word of element (N-1)/2, N-1 odd) if int64.
__device__ __forceinline__ bool idx_is64(const void* p, int N) {
    return ((const int*)p)[N - 1] == 0;
}
__device__ __forceinline__ int load_idx(const void* p, long long i, bool is64) {
    return is64 ? (int)((const long long*)p)[i] : ((const int*)p)[i];
}

// ws layout:
//   [0,              NSEG*CIN)           float seg_sum[16][64]   (4 KB)
//   [NSEG*CIN,       NSEG*CIN+NSEG*COUT) float h_final[16][128]  (8 KB)

__global__ __launch_bounds__(256) void k_zero(float* __restrict__ seg_sum) {
    for (int i = threadIdx.x; i < NSEG * CIN; i += 256) seg_sum[i] = 0.0f;
}

// Segment-sum: contiguous chunk per block; sorted indices => ~1-2 segments/chunk.
// Thread owns one float4 column-slice (q4) and walks rows with stride 16.
__global__ __launch_bounds__(256) void k_segsum(const float* __restrict__ feat,
                                                const void* __restrict__ idx,
                                                float* __restrict__ seg_sum,
                                                int N, int rows_per_blk) {
    __shared__ float acc_lds[NSEG * CIN];
    const int tid = threadIdx.x;
    for (int i = tid; i < NSEG * CIN; i += 256) acc_lds[i] = 0.0f;
    __syncthreads();

    const bool is64 = idx_is64(idx, N);
    const int q4 = (tid & 15) * 4;        // float offset within row (16B aligned)
    const int row0 = blockIdx.x * rows_per_blk;
    const int row_end = min(row0 + rows_per_blk, N);

    vf4 acc = {0.f, 0.f, 0.f, 0.f};
    int cur = -1;
    for (int r = row0 + (tid >> 4); r < row_end; r += 16) {
        const int s = load_idx(idx, r, is64);
        if (s != cur) {
            if (cur >= 0) {
                atomicAdd(&acc_lds[cur * CIN + q4 + 0], acc.x);
                atomicAdd(&acc_lds[cur * CIN + q4 + 1], acc.y);
                atomicAdd(&acc_lds[cur * CIN + q4 + 2], acc.z);
                atomicAdd(&acc_lds[cur * CIN + q4 + 3], acc.w);
            }
            acc = (vf4){0.f, 0.f, 0.f, 0.f};
            cur = s;
        }
        const vf4 v = *(const vf4*)(feat + (size_t)r * CIN + q4);
        acc += v;
    }
    if (cur >= 0) {
        atomicAdd(&acc_lds[cur * CIN + q4 + 0], acc.x);
        atomicAdd(&acc_lds[cur * CIN + q4 + 1], acc.y);
        atomicAdd(&acc_lds[cur * CIN + q4 + 2], acc.z);
        atomicAdd(&acc_lds[cur * CIN + q4 + 3], acc.w);
    }
    __syncthreads();
    // Block flush: skip zeros (untouched segments) -> ~128 global atomics/block.
    for (int i = tid; i < NSEG * CIN; i += 256) {
        const float v = acc_lds[i];
        if (v != 0.0f) atomicAdd(&seg_sum[i], v);
    }
}

// Single block: counts via binary search, pooled mean, 16x64 @ 64x128 dot,
// BatchNorm (biased variance over 16), ReLU -> h_final[16][128].
__global__ __launch_bounds__(256) void k_mlp(const float* __restrict__ seg_sum,
                                             const void* __restrict__ idx, int N,
                                             const float* __restrict__ W,
                                             const float* __restrict__ gamma,
                                             const float* __restrict__ beta,
                                             float* __restrict__ h_final) {
    __shared__ float pooled[NSEG * CIN];     // 4 KB
    __shared__ float h_lds[NSEG * COUT];     // 8 KB
    __shared__ float cnt[NSEG];
    __shared__ float scale_s[COUT], bias_s[COUT];
    __shared__ int bnd[NSEG + 1];
    const int tid = threadIdx.x;
    const bool is64 = idx_is64(idx, N);

    if (tid <= NSEG) {
        if (tid == 0) bnd[0] = 0;
        else if (tid == NSEG) bnd[NSEG] = N;
        else {
            int lo = 0, hi = N;
            while (lo < hi) {
                const int mid = (lo + hi) >> 1;
                if (load_idx(idx, mid, is64) < tid) lo = mid + 1; else hi = mid;
            }
            bnd[tid] = lo;
        }
    }
    __syncthreads();
    if (tid < NSEG) cnt[tid] = (float)max(bnd[tid + 1] - bnd[tid], 1);
    __syncthreads();
    for (int i = tid; i < NSEG * CIN; i += 256) pooled[i] = seg_sum[i] / cnt[i / CIN];
    __syncthreads();

    const int co = tid & 127;
    const int half = tid >> 7;
    float w[CIN];
    #pragma unroll
    for (int c = 0; c < CIN; c += 4)
        *(vf4*)(w + c) = *(const vf4*)(W + (size_t)co * CIN + c);
    for (int b = half; b < NSEG; b += 2) {
        float a = 0.f;
        #pragma unroll
        for (int c = 0; c < CIN; ++c) a += pooled[b * CIN + c] * w[c];
        h_lds[b * COUT + co] = a;
    }
    __syncthreads();

    if (tid < COUT) {
        float m = 0.f;
        #pragma unroll
        for (int b = 0; b < NSEG; ++b) m += h_lds[b * COUT + tid];
        m *= (1.0f / NSEG);
        float v = 0.f;
        #pragma unroll
        for (int b = 0; b < NSEG; ++b) {
            const float d = h_lds[b * COUT + tid] - m;
            v += d * d;
        }
        v *= (1.0f / NSEG);
        const float sc = gamma[tid] * rsqrtf(v + BN_EPS);
        scale_s[tid] = sc;
        bias_s[tid] = beta[tid] - m * sc;
    }
    __syncthreads();
    for (int b = half; b < NSEG; b += 2) {
        const float hv = h_lds[b * COUT + co] * scale_s[co] + bias_s[co];
        h_final[b * COUT + co] = fmaxf(hv, 0.0f);
    }
}

// Gather: out[n,:] = h_final[idx[n],:]. 16 rows x 512B live in LDS; each thread
// streams one float4/iter, nontemporal (512 MB pure write).
__global__ __launch_bounds__(256) void k_gather(const float* __restrict__ h_final,
                                                const void* __restrict__ idx,
                                                float* __restrict__ out, int N) {
    __shared__ vf4 h4[NSEG * 32];
    const int tid = threadIdx.x;
    for (int i = tid; i < NSEG * 32; i += 256) h4[i] = ((const vf4*)h_final)[i];
    const bool is64 = idx_is64(idx, N);
    __syncthreads();

    vf4* out4 = (vf4*)out;
    const long long total = (long long)N * 32;
    const long long stride = (long long)gridDim.x * 256;
    for (long long i = (long long)blockIdx.x * 256 + tid; i < total; i += stride) {
        const int row = (int)(i >> 5);
        const int q = (int)(i & 31);
        const int s = load_idx(idx, row, is64);
        __builtin_nontemporal_store(h4[s * 32 + q], &out4[i]);
    }
}

extern "C" void kernel_launch(void* const* d_in, const int* in_sizes, int n_in,
                              void* d_out, int out_size, void* d_ws, size_t ws_size,
                              hipStream_t stream) {
    const float* feat  = (const float*)d_in[0];
    const float* W     = (const float*)d_in[1];
    const float* gamma = (const float*)d_in[2];
    const float* beta  = (const float*)d_in[3];
    const void*  idx   = d_in[4];
    const int N = in_sizes[4];

    float* seg_sum = (float*)d_ws;
    float* h_final = (float*)d_ws + NSEG * CIN;

    hipLaunchKernelGGL(k_zero, dim3(1), dim3(256), 0, stream, seg_sum);

    const int NB = 1024;
    const int rows_per_blk = (((N + NB - 1) / NB) + 15) & ~15;
    hipLaunchKernelGGL(k_segsum, dim3(NB), dim3(256), 0, stream,
                       feat, idx, seg_sum, N, rows_per_blk);

    hipLaunchKernelGGL(k_mlp, dim3(1), dim3(256), 0, stream,
                       seg_sum, idx, N, W, gamma, beta, h_final);

    hipLaunchKernelGGL(k_gather, dim3(2048), dim3(256), 0, stream,
                       h_final, idx, (float*)d_out, N);
}